// Round 16
// baseline (3697.075 us; speedup 1.0000x reference)
//
#include <hip/hip_runtime.h>
#include <hip/hip_bf16.h>

#define NCL   300000
#define NLIT  200000
#define HALFL 100000
#define NVAR  100000

#define NB_C  293            // 293*1024 = 300032 >= NCL
#define PAD_C (NB_C*1024)
#define NB_L  196            // 196*1024 = 200704 >= NLIT
#define PAD_L (NB_L*1024)

typedef __attribute__((ext_vector_type(8))) short short8;   // 8 bf16 (4 VGPRs)
typedef __attribute__((ext_vector_type(4))) float f32x4;    // MFMA acc

__device__ __forceinline__ unsigned short f2b(float x){     // fp32 -> bf16 RNE
  union{float f; unsigned int u;} v; v.f = x;
  unsigned int r = v.u + 0x7FFF + ((v.u >> 16) & 1);
  return (unsigned short)(r >> 16);
}
__device__ __forceinline__ float b2f(unsigned short u){
  union{unsigned int i; float f;} x; x.i = ((unsigned int)u) << 16; return x.f;
}
__device__ __forceinline__ void split3(float x, unsigned short& h, unsigned short& m, unsigned short& l){
  h = f2b(x); float r1 = x - b2f(h);
  m = f2b(r1); l = f2b(r1 - b2f(m));
}
__device__ __forceinline__ int imax(int a, int b){ return a > b ? a : b; }

// ---------------------------------------------------------------- utilities
__global__ void k_init_lh(const float* __restrict__ L0, float* __restrict__ Lh){
  int i = blockIdx.x*256 + threadIdx.x;            // 25,600,000 total
  Lh[i] = L0[i & 127];
}

__global__ void k_zero4(float4* __restrict__ p, int n4){
  int i = blockIdx.x*256 + threadIdx.x;
  if(i < n4) p[i] = make_float4(0.f,0.f,0.f,0.f);
}

// Pack fp32 row-major W[K][N] into bf16 MFMA B-fragment order (2 planes):
// frag[((nt*(K/32)+kt)*64 + lane)*8 + j] <- W[kt*32+(lane>>4)*8+j][nt*16+(lane&15)]
__global__ void k_pack_w(const float* __restrict__ W, short* __restrict__ Whi,
                         short* __restrict__ Wlo, int K, int N){
  int i = blockIdx.x*256 + threadIdx.x;
  if(i >= K*N) return;
  int j  = i & 7;
  int L  = (i >> 3) & 63;
  int kt = (i >> 9) % (K >> 5);
  int nt = (i >> 9) / (K >> 5);
  int k = kt*32 + ((L >> 4) << 3) + j;
  int n = nt*16 + (L & 15);
  float w = W[(size_t)k*N + n];
  unsigned short hi = f2b(w);
  Whi[i] = (short)hi;
  Wlo[i] = (short)f2b(w - b2f(hi));
}

// 3-plane variant (hi/mid/lo)
__global__ void k_pack_w3(const float* __restrict__ W, short* __restrict__ Wh,
                          short* __restrict__ Wm, short* __restrict__ Wl, int K, int N){
  int i = blockIdx.x*256 + threadIdx.x;
  if(i >= K*N) return;
  int j  = i & 7;
  int L  = (i >> 3) & 63;
  int kt = (i >> 9) % (K >> 5);
  int nt = (i >> 9) / (K >> 5);
  int k = kt*32 + ((L >> 4) << 3) + j;
  int n = nt*16 + (L & 15);
  unsigned short h, m, l;
  split3(W[(size_t)k*N + n], h, m, l);
  Wh[i] = (short)h; Wm[i] = (short)m; Wl[i] = (short)l;
}

// ---------------------------------------------------------------- CSR build
__global__ __launch_bounds__(256) void k_hist(const int* __restrict__ ci, const int* __restrict__ li,
    int* __restrict__ Pc, int* __restrict__ Pl, int ne){
  int e = blockIdx.x*256 + threadIdx.x;
  if(e < ne){ atomicAdd(&Pc[ci[e]], 1); atomicAdd(&Pl[li[e]], 1); }
}

__global__ __launch_bounds__(256) void k_scan_pass1(const int* __restrict__ P, int* __restrict__ psum){
  __shared__ int red[256];
  int t = threadIdx.x;
  int4 v = *(const int4*)&P[blockIdx.x*1024 + t*4];
  red[t] = v.x + v.y + v.z + v.w;
  __syncthreads();
  for(int ofs=128; ofs>0; ofs>>=1){
    if(t < ofs) red[t] += red[t+ofs];
    __syncthreads();
  }
  if(t == 0) psum[blockIdx.x] = red[0];
}

__global__ __launch_bounds__(512) void k_scan_pass2(int* __restrict__ psum, int nb){
  __shared__ int sA[512], sB[512];
  int t = threadIdx.x;
  sA[t] = (t < nb) ? psum[t] : 0;
  __syncthreads();
  int* src = sA; int* dst = sB;
  for(int ofs=1; ofs<512; ofs<<=1){
    int x = src[t];
    if(t >= ofs) x += src[t-ofs];
    dst[t] = x;
    __syncthreads();
    int* tmp = src; src = dst; dst = tmp;
  }
  psum[t] = t ? src[t-1] : 0;    // exclusive
}

__global__ __launch_bounds__(256) void k_scan_pass3(int* __restrict__ P, const int* __restrict__ psum){
  __shared__ int sA[256], sB[256];
  int t = threadIdx.x;
  int base = blockIdx.x*1024 + t*4;
  int4 v = *(const int4*)&P[base];
  int tsum = v.x + v.y + v.z + v.w;
  sA[t] = tsum;
  __syncthreads();
  int* src = sA; int* dst = sB;
  for(int ofs=1; ofs<256; ofs<<=1){
    int x = src[t];
    if(t >= ofs) x += src[t-ofs];
    dst[t] = x;
    __syncthreads();
    int* tmp = src; src = dst; dst = tmp;
  }
  int excl = psum[blockIdx.x] + src[t] - tsum;   // exclusive across whole array
  int4 o;
  o.x = excl;
  o.y = o.x + v.x;
  o.z = o.y + v.y;
  o.w = o.z + v.z;
  *(int4*)&P[base] = o;
}

// After k_fill, P[c] holds END offset of row c; begin(c) = c ? P[c-1] : 0.
__global__ __launch_bounds__(256) void k_fill(const int* __restrict__ ci, const int* __restrict__ li,
    int* __restrict__ Pc, int* __restrict__ Pl, int* __restrict__ clit, int* __restrict__ lcl, int ne){
  int e = blockIdx.x*256 + threadIdx.x;
  if(e < ne){
    int c = ci[e], l = li[e];
    clit[atomicAdd(&Pc[c], 1)] = l;
    lcl [atomicAdd(&Pl[l], 1)] = c;
  }
}

// ------ clause side: CSR gather + 3-PLANE bf16 MFMA MLP 256->256->128
// X*W = Xh*Wh + (Xh*Wm + Xm*Wh) + (Xh*Wl + Xm*Wm + Xl*Wh); error ~2^-27.
// 256 thr, 32 clauses/block, xs[3][32][264] planes (50.7 KB).
__global__ __launch_bounds__(256) void k_clause_fused(
    const int* __restrict__ Pc, const int* __restrict__ clit,
    const float* __restrict__ Lh,
    const short* __restrict__ W1h, const short* __restrict__ W1m, const short* __restrict__ W1l,
    const float* __restrict__ b1,
    const short* __restrict__ W2h, const short* __restrict__ W2m, const short* __restrict__ W2l,
    const float* __restrict__ b2,
    float* __restrict__ Y){
  __shared__ short xs[3][32][264];
  __shared__ int rng[33];
  const int t = threadIdx.x;
  const int r0 = blockIdx.x * 32;

  if(t < 33) rng[t] = (r0 + t == 0) ? 0 : Pc[r0 + t - 1];
  __syncthreads();

  const int lane = t & 63, wv = t >> 6;
  { // gather: lanes 0-31 direct half, 32-63 flipped; 4 interleaved chains
    const int half = lane >> 5, f4 = (lane & 31) * 4;
    #pragma unroll
    for(int g=0; g<2; g++){
      const int rb4 = wv*8 + g*4;
      const int e0=rng[rb4+0], d0=rng[rb4+1]-e0;
      const int e1=rng[rb4+1], d1=rng[rb4+2]-e1;
      const int e2=rng[rb4+2], d2=rng[rb4+3]-e2;
      const int e3=rng[rb4+3], d3=rng[rb4+4]-e3;
      float4 a0=make_float4(0.f,0.f,0.f,0.f), a1=a0, a2=a0, a3=a0;
      int l0=(d0>0)?clit[e0]:0, l1=(d1>0)?clit[e1]:0;
      int l2=(d2>0)?clit[e2]:0, l3=(d3>0)?clit[e3]:0;
      const int md = imax(imax(d0,d1), imax(d2,d3));
      for(int s=0; s<md; s++){
        int s0 = half ? ((l0<HALFL)?l0+HALFL:l0-HALFL) : l0;
        int s1 = half ? ((l1<HALFL)?l1+HALFL:l1-HALFL) : l1;
        int s2 = half ? ((l2<HALFL)?l2+HALFL:l2-HALFL) : l2;
        int s3 = half ? ((l3<HALFL)?l3+HALFL:l3-HALFL) : l3;
        float4 v0 = *(const float4*)&Lh[(size_t)s0*128 + f4];
        float4 v1 = *(const float4*)&Lh[(size_t)s1*128 + f4];
        float4 v2 = *(const float4*)&Lh[(size_t)s2*128 + f4];
        float4 v3 = *(const float4*)&Lh[(size_t)s3*128 + f4];
        int p0=(s+1<d0)?clit[e0+s+1]:0;
        int p1=(s+1<d1)?clit[e1+s+1]:0;
        int p2=(s+1<d2)?clit[e2+s+1]:0;
        int p3=(s+1<d3)?clit[e3+s+1]:0;
        float m0=(s<d0)?1.f:0.f, m1=(s<d1)?1.f:0.f;
        float m2=(s<d2)?1.f:0.f, m3=(s<d3)?1.f:0.f;
        a0.x=fmaf(m0,v0.x,a0.x); a0.y=fmaf(m0,v0.y,a0.y); a0.z=fmaf(m0,v0.z,a0.z); a0.w=fmaf(m0,v0.w,a0.w);
        a1.x=fmaf(m1,v1.x,a1.x); a1.y=fmaf(m1,v1.y,a1.y); a1.z=fmaf(m1,v1.z,a1.z); a1.w=fmaf(m1,v1.w,a1.w);
        a2.x=fmaf(m2,v2.x,a2.x); a2.y=fmaf(m2,v2.y,a2.y); a2.z=fmaf(m2,v2.z,a2.z); a2.w=fmaf(m2,v2.w,a2.w);
        a3.x=fmaf(m3,v3.x,a3.x); a3.y=fmaf(m3,v3.y,a3.y); a3.z=fmaf(m3,v3.z,a3.z); a3.w=fmaf(m3,v3.w,a3.w);
        l0=p0; l1=p1; l2=p2; l3=p3;
      }
      float4 aa[4] = {a0, a1, a2, a3};
      #pragma unroll
      for(int i=0;i<4;i++){
        float4 a = aa[i];
        unsigned short hx,mx,lx, hy,my,ly, hz,mz,lz, hw,mw,lw;
        split3(a.x,hx,mx,lx); split3(a.y,hy,my,ly);
        split3(a.z,hz,mz,lz); split3(a.w,hw,mw,lw);
        int off = half*128 + f4;
        *(uint2*)&xs[0][rb4+i][off] = make_uint2(((unsigned int)hy<<16)|hx, ((unsigned int)hw<<16)|hz);
        *(uint2*)&xs[1][rb4+i][off] = make_uint2(((unsigned int)my<<16)|mx, ((unsigned int)mw<<16)|mz);
        *(uint2*)&xs[2][rb4+i][off] = make_uint2(((unsigned int)ly<<16)|lx, ((unsigned int)lw<<16)|lz);
      }
    }
  }
  __syncthreads();

  const int rt  = wv & 1;
  const int ntb = (wv >> 1) * 8;
  const int am  = rt*16 + (lane & 15);
  const int ak  = (lane >> 4) * 8;

  // layer 1: 256 -> 256
  f32x4 acc[8];
  #pragma unroll
  for(int ntl=0; ntl<8; ntl++){
    float bv = b1[(ntb+ntl)*16 + (lane & 15)];
    acc[ntl] = (f32x4){bv, bv, bv, bv};
  }
  {
    const short8* Bh = (const short8*)W1h;
    const short8* Bm = (const short8*)W1m;
    const short8* Bl = (const short8*)W1l;
    #pragma unroll
    for(int kt=0; kt<8; kt++){
      short8 ah = *(const short8*)&xs[0][am][kt*32 + ak];
      short8 am8= *(const short8*)&xs[1][am][kt*32 + ak];
      short8 al = *(const short8*)&xs[2][am][kt*32 + ak];
      #pragma unroll
      for(int ntl=0; ntl<8; ntl++){
        int g = ntb + ntl;
        short8 bh = Bh[(g*8 + kt)*64 + lane];
        short8 bm = Bm[(g*8 + kt)*64 + lane];
        short8 bl = Bl[(g*8 + kt)*64 + lane];
        acc[ntl] = __builtin_amdgcn_mfma_f32_16x16x32_bf16(ah,  bh, acc[ntl], 0, 0, 0);
        acc[ntl] = __builtin_amdgcn_mfma_f32_16x16x32_bf16(ah,  bm, acc[ntl], 0, 0, 0);
        acc[ntl] = __builtin_amdgcn_mfma_f32_16x16x32_bf16(am8, bh, acc[ntl], 0, 0, 0);
        acc[ntl] = __builtin_amdgcn_mfma_f32_16x16x32_bf16(ah,  bl, acc[ntl], 0, 0, 0);
        acc[ntl] = __builtin_amdgcn_mfma_f32_16x16x32_bf16(am8, bm, acc[ntl], 0, 0, 0);
        acc[ntl] = __builtin_amdgcn_mfma_f32_16x16x32_bf16(al,  bh, acc[ntl], 0, 0, 0);
      }
    }
  }
  __syncthreads();
  #pragma unroll
  for(int ntl=0; ntl<8; ntl++){
    int col = (ntb + ntl)*16 + (lane & 15);
    int rowb = rt*16 + ((lane >> 4) << 2);
    #pragma unroll
    for(int reg=0; reg<4; reg++){
      float v = fmaxf(acc[ntl][reg], 0.f);
      unsigned short h, m, l;
      split3(v, h, m, l);
      xs[0][rowb + reg][col] = (short)h;
      xs[1][rowb + reg][col] = (short)m;
      xs[2][rowb + reg][col] = (short)l;
    }
  }
  __syncthreads();

  // layer 2: 256 -> 128
  const int ntb2 = (wv >> 1) * 4;
  f32x4 o4[4];
  #pragma unroll
  for(int ntl=0; ntl<4; ntl++){
    float bv = b2[(ntb2+ntl)*16 + (lane & 15)];
    o4[ntl] = (f32x4){bv, bv, bv, bv};
  }
  {
    const short8* Bh = (const short8*)W2h;
    const short8* Bm = (const short8*)W2m;
    const short8* Bl = (const short8*)W2l;
    #pragma unroll
    for(int kt=0; kt<8; kt++){
      short8 ah = *(const short8*)&xs[0][am][kt*32 + ak];
      short8 am8= *(const short8*)&xs[1][am][kt*32 + ak];
      short8 al = *(const short8*)&xs[2][am][kt*32 + ak];
      #pragma unroll
      for(int ntl=0; ntl<4; ntl++){
        int g = ntb2 + ntl;
        short8 bh = Bh[(g*8 + kt)*64 + lane];
        short8 bm = Bm[(g*8 + kt)*64 + lane];
        short8 bl = Bl[(g*8 + kt)*64 + lane];
        o4[ntl] = __builtin_amdgcn_mfma_f32_16x16x32_bf16(ah,  bh, o4[ntl], 0, 0, 0);
        o4[ntl] = __builtin_amdgcn_mfma_f32_16x16x32_bf16(ah,  bm, o4[ntl], 0, 0, 0);
        o4[ntl] = __builtin_amdgcn_mfma_f32_16x16x32_bf16(am8, bh, o4[ntl], 0, 0, 0);
        o4[ntl] = __builtin_amdgcn_mfma_f32_16x16x32_bf16(ah,  bl, o4[ntl], 0, 0, 0);
        o4[ntl] = __builtin_amdgcn_mfma_f32_16x16x32_bf16(am8, bm, o4[ntl], 0, 0, 0);
        o4[ntl] = __builtin_amdgcn_mfma_f32_16x16x32_bf16(al,  bh, o4[ntl], 0, 0, 0);
      }
    }
  }
  #pragma unroll
  for(int ntl=0; ntl<4; ntl++){
    int col = (ntb2 + ntl)*16 + (lane & 15);
    int rowb = r0 + rt*16 + ((lane >> 4) << 2);
    #pragma unroll
    for(int reg=0; reg<4; reg++)
      Y[(size_t)(rowb + reg)*128 + col] = o4[ntl][reg];
  }
}

// ---------------------------------------------------------------- col stats
__global__ __launch_bounds__(256) void k_colstats(const float* __restrict__ C, float* __restrict__ st){
  const int t = threadIdx.x, col = t & 127, h = t >> 7;
  float s = 0.f, s2 = 0.f;
  for(int r = blockIdx.x*2 + h; r < NCL; r += 1024){   // grid = 512 blocks
    float v = C[(size_t)r*128 + col];
    s += v; s2 += v*v;
  }
  __shared__ float red[256];
  red[t] = s; __syncthreads();
  if(t < 128) atomicAdd(&st[col], red[t] + red[t+128]);
  __syncthreads();
  red[t] = s2; __syncthreads();
  if(t < 128) atomicAdd(&st[128+col], red[t] + red[t+128]);
}

__global__ void k_finstats(float* st){
  int j = threadIdx.x;
  if(j < 128){
    const float n = (float)NCL;
    float mean = st[j]/n;
    float var = (st[128+j] - n*mean*mean) / (n - 1.f);   // ddof=1
    var = fmaxf(var, 0.f);
    st[256+j] = mean;
    st[384+j] = 1.f/(sqrtf(var) + 1e-10f);
  }
}

// -- literal side: gather(normalized) + 3-PLANE bf16 MFMA 128->128->128
//    + 0.1*residual + LayerNorm. 256 thr, 32 lits/block.
__global__ __launch_bounds__(256) void k_lit_fused(
    const int* __restrict__ Pl, const int* __restrict__ lcl,
    const float* __restrict__ C, const float* __restrict__ st,
    const short* __restrict__ W1h, const short* __restrict__ W1m, const short* __restrict__ W1l,
    const float* __restrict__ b1,
    const short* __restrict__ W2h, const short* __restrict__ W2m, const short* __restrict__ W2l,
    const float* __restrict__ b2,
    const float* __restrict__ lng, const float* __restrict__ lnb, float* __restrict__ Lh){
  __shared__ short xs[3][32][136];
  __shared__ int rng[33];
  float* ys = (float*)&xs[0][0][0];          // [32][132] fp32, aliases xs
  const int t = threadIdx.x;
  const int r0 = blockIdx.x * 32;

  if(t < 33) rng[t] = (r0 + t == 0) ? 0 : Pl[r0 + t - 1];
  __syncthreads();

  const int lane = t & 63, wv = t >> 6;
  { // gather: half-wave 4 interleaved row-chains; f4/lane covers 128
    const int half = lane >> 5, f4 = (lane & 31) * 4;
    float4 mean4 = *(const float4*)&st[256+f4];
    float4 isd4  = *(const float4*)&st[384+f4];
    const int rb4 = wv*8 + half*4;
    const int e0=rng[rb4+0], d0=rng[rb4+1]-e0;
    const int e1=rng[rb4+1], d1=rng[rb4+2]-e1;
    const int e2=rng[rb4+2], d2=rng[rb4+3]-e2;
    const int e3=rng[rb4+3], d3=rng[rb4+4]-e3;
    float4 a0=make_float4(0.f,0.f,0.f,0.f), a1=a0, a2=a0, a3=a0;
    int l0=(d0>0)?lcl[e0]:0, l1=(d1>0)?lcl[e1]:0;
    int l2=(d2>0)?lcl[e2]:0, l3=(d3>0)?lcl[e3]:0;
    const int md = imax(imax(d0,d1), imax(d2,d3));
    for(int s=0; s<md; s++){
      float4 v0 = *(const float4*)&C[(size_t)l0*128 + f4];
      float4 v1 = *(const float4*)&C[(size_t)l1*128 + f4];
      float4 v2 = *(const float4*)&C[(size_t)l2*128 + f4];
      float4 v3 = *(const float4*)&C[(size_t)l3*128 + f4];
      int p0=(s+1<d0)?lcl[e0+s+1]:0;
      int p1=(s+1<d1)?lcl[e1+s+1]:0;
      int p2=(s+1<d2)?lcl[e2+s+1]:0;
      int p3=(s+1<d3)?lcl[e3+s+1]:0;
      float m0=(s<d0)?1.f:0.f, m1=(s<d1)?1.f:0.f;
      float m2=(s<d2)?1.f:0.f, m3=(s<d3)?1.f:0.f;
      a0.x=fmaf(m0,v0.x,a0.x); a0.y=fmaf(m0,v0.y,a0.y); a0.z=fmaf(m0,v0.z,a0.z); a0.w=fmaf(m0,v0.w,a0.w);
      a1.x=fmaf(m1,v1.x,a1.x); a1.y=fmaf(m1,v1.y,a1.y); a1.z=fmaf(m1,v1.z,a1.z); a1.w=fmaf(m1,v1.w,a1.w);
      a2.x=fmaf(m2,v2.x,a2.x); a2.y=fmaf(m2,v2.y,a2.y); a2.z=fmaf(m2,v2.z,a2.z); a2.w=fmaf(m2,v2.w,a2.w);
      a3.x=fmaf(m3,v3.x,a3.x); a3.y=fmaf(m3,v3.y,a3.y); a3.z=fmaf(m3,v3.z,a3.z); a3.w=fmaf(m3,v3.w,a3.w);
      l0=p0; l1=p1; l2=p2; l3=p3;
    }
    float4 aa[4] = {a0, a1, a2, a3};
    float dd[4] = {(float)d0, (float)d1, (float)d2, (float)d3};
    #pragma unroll
    for(int i=0;i<4;i++){
      float4 a = aa[i];
      float dg = dd[i];
      a.x = (a.x - dg*mean4.x)*isd4.x; a.y = (a.y - dg*mean4.y)*isd4.y;
      a.z = (a.z - dg*mean4.z)*isd4.z; a.w = (a.w - dg*mean4.w)*isd4.w;
      unsigned short hx,mx,lx, hy,my,ly, hz,mz,lz, hw,mw,lw;
      split3(a.x,hx,mx,lx); split3(a.y,hy,my,ly);
      split3(a.z,hz,mz,lz); split3(a.w,hw,mw,lw);
      *(uint2*)&xs[0][rb4+i][f4] = make_uint2(((unsigned int)hy<<16)|hx, ((unsigned int)hw<<16)|hz);
      *(uint2*)&xs[1][rb4+i][f4] = make_uint2(((unsigned int)my<<16)|mx, ((unsigned int)mw<<16)|mz);
      *(uint2*)&xs[2][rb4+i][f4] = make_uint2(((unsigned int)ly<<16)|lx, ((unsigned int)lw<<16)|lz);
    }
  }
  __syncthreads();

  const int rt  = wv & 1;                 // row-tile (rows rt*16..+15)
  const int ntb = (wv >> 1) * 4;          // 4 n-tiles per wave-pair (128 cols)
  const int am  = rt*16 + (lane & 15);
  const int ak  = (lane >> 4) * 8;

  // layer 1: 128 -> 128 (kt in 0..3)
  f32x4 acc[4];
  #pragma unroll
  for(int ntl=0; ntl<4; ntl++){
    float bv = b1[(ntb+ntl)*16 + (lane & 15)];
    acc[ntl] = (f32x4){bv, bv, bv, bv};
  }
  {
    const short8* Bh = (const short8*)W1h;
    const short8* Bm = (const short8*)W1m;
    const short8* Bl = (const short8*)W1l;
    #pragma unroll
    for(int kt=0; kt<4; kt++){
      short8 ah = *(const short8*)&xs[0][am][kt*32 + ak];
      short8 am8= *(const short8*)&xs[1][am][kt*32 + ak];
      short8 al = *(const short8*)&xs[2][am][kt*32 + ak];
      #pragma unroll
      for(int ntl=0; ntl<4; ntl++){
        int g = ntb + ntl;
        short8 bh = Bh[(g*4 + kt)*64 + lane];
        short8 bm = Bm[(g*4 + kt)*64 + lane];
        short8 bl = Bl[(g*4 + kt)*64 + lane];
        acc[ntl] = __builtin_amdgcn_mfma_f32_16x16x32_bf16(ah,  bh, acc[ntl], 0, 0, 0);
        acc[ntl] = __builtin_amdgcn_mfma_f32_16x16x32_bf16(ah,  bm, acc[ntl], 0, 0, 0);
        acc[ntl] = __builtin_amdgcn_mfma_f32_16x16x32_bf16(am8, bh, acc[ntl], 0, 0, 0);
        acc[ntl] = __builtin_amdgcn_mfma_f32_16x16x32_bf16(ah,  bl, acc[ntl], 0, 0, 0);
        acc[ntl] = __builtin_amdgcn_mfma_f32_16x16x32_bf16(am8, bm, acc[ntl], 0, 0, 0);
        acc[ntl] = __builtin_amdgcn_mfma_f32_16x16x32_bf16(al,  bh, acc[ntl], 0, 0, 0);
      }
    }
  }
  __syncthreads();
  // hidden: ReLU -> 3-plane bf16, overwrite xs
  #pragma unroll
  for(int ntl=0; ntl<4; ntl++){
    int col = (ntb + ntl)*16 + (lane & 15);
    int rowb = rt*16 + ((lane >> 4) << 2);
    #pragma unroll
    for(int reg=0; reg<4; reg++){
      float v = fmaxf(acc[ntl][reg], 0.f);
      unsigned short h, m, l;
      split3(v, h, m, l);
      xs[0][rowb + reg][col] = (short)h;
      xs[1][rowb + reg][col] = (short)m;
      xs[2][rowb + reg][col] = (short)l;
    }
  }
  __syncthreads();

  // layer 2: 128 -> 128 (A-frags loaded upfront, then xs is reused as ys)
  short8 a2h[4], a2m[4], a2l[4];
  #pragma unroll
  for(int kt=0; kt<4; kt++){
    a2h[kt] = *(const short8*)&xs[0][am][kt*32 + ak];
    a2m[kt] = *(const short8*)&xs[1][am][kt*32 + ak];
    a2l[kt] = *(const short8*)&xs[2][am][kt*32 + ak];
  }
  __syncthreads();                         // all xs reads done -> ys writable
  f32x4 o4[4];
  #pragma unroll
  for(int ntl=0; ntl<4; ntl++){
    float bv = b2[(ntb+ntl)*16 + (lane & 15)];
    o4[ntl] = (f32x4){bv, bv, bv, bv};
  }
  {
    const short8* Bh = (const short8*)W2h;
    const short8* Bm = (const short8*)W2m;
    const short8* Bl = (const short8*)W2l;
    #pragma unroll
    for(int kt=0; kt<4; kt++){
      #pragma unroll
      for(int ntl=0; ntl<4; ntl++){
        int g = ntb + ntl;
        short8 bh = Bh[(g*4 + kt)*64 + lane];
        short8 bm = Bm[(g*4 + kt)*64 + lane];
        short8 bl = Bl[(g*4 + kt)*64 + lane];
        o4[ntl] = __builtin_amdgcn_mfma_f32_16x16x32_bf16(a2h[kt], bh, o4[ntl], 0, 0, 0);
        o4[ntl] = __builtin_amdgcn_mfma_f32_16x16x32_bf16(a2h[kt], bm, o4[ntl], 0, 0, 0);
        o4[ntl] = __builtin_amdgcn_mfma_f32_16x16x32_bf16(a2m[kt], bh, o4[ntl], 0, 0, 0);
        o4[ntl] = __builtin_amdgcn_mfma_f32_16x16x32_bf16(a2h[kt], bl, o4[ntl], 0, 0, 0);
        o4[ntl] = __builtin_amdgcn_mfma_f32_16x16x32_bf16(a2m[kt], bm, o4[ntl], 0, 0, 0);
        o4[ntl] = __builtin_amdgcn_mfma_f32_16x16x32_bf16(a2l[kt], bh, o4[ntl], 0, 0, 0);
      }
    }
  }
  #pragma unroll
  for(int ntl=0; ntl<4; ntl++){
    int col = (ntb + ntl)*16 + (lane & 15);
    int rowb = rt*16 + ((lane >> 4) << 2);
    #pragma unroll
    for(int reg=0; reg<4; reg++)
      ys[(rowb + reg)*132 + col] = o4[ntl][reg];
  }
  __syncthreads();

  { // residual + LayerNorm: 8 threads per row, 16 cols each
    const int r  = t >> 3;                 // 0..31
    const int cg = (t & 7) * 16;
    size_t row = (size_t)(r0 + r);
    float y[16];
    #pragma unroll
    for(int jj=0; jj<16; jj+=4){
      float4 v = *(const float4*)&ys[r*132 + cg + jj];
      float4 la = *(const float4*)&Lh[row*128 + cg + jj];
      y[jj]   = v.x + 0.1f*la.x; y[jj+1] = v.y + 0.1f*la.y;
      y[jj+2] = v.z + 0.1f*la.z; y[jj+3] = v.w + 0.1f*la.w;
    }
    float s = 0.f, s2 = 0.f;
    #pragma unroll
    for(int jj=0; jj<16; jj++){ s += y[jj]; s2 += y[jj]*y[jj]; }
    #pragma unroll
    for(int m=1; m<8; m<<=1){ s += __shfl_xor(s,m,64); s2 += __shfl_xor(s2,m,64); }
    float mean = s*(1.f/128.f);
    float var  = s2*(1.f/128.f) - mean*mean;
    float rs   = rsqrtf(fmaxf(var, 0.f) + 1e-5f);
    #pragma unroll
    for(int jj=0; jj<16; jj+=4){
      float4 gv = *(const float4*)&lng[cg + jj];
      float4 bv = *(const float4*)&lnb[cg + jj];
      *(float4*)&Lh[row*128 + cg + jj] = make_float4(
        (y[jj]  -mean)*rs*gv.x + bv.x, (y[jj+1]-mean)*rs*gv.y + bv.y,
        (y[jj+2]-mean)*rs*gv.z + bv.z, (y[jj+3]-mean)*rs*gv.w + bv.w);
    }
  }
}

// ------------ head_v: compensated 2-plane bf16 MFMA, 256 thr, 32 vars/block
__global__ __launch_bounds__(256) void k_head_v(const float* __restrict__ Lh,
    const short* __restrict__ Wdh, const short* __restrict__ Wdl,
    const float* __restrict__ b1d, const float* __restrict__ W2d, const float* __restrict__ b2d,
    const short* __restrict__ Wch, const short* __restrict__ Wcl,
    const float* __restrict__ b1c, const float* __restrict__ W2c, const float* __restrict__ b2c,
    float* __restrict__ out){
  __shared__ short xs[2][32][264];
  __shared__ float hpart[32][2];
  const int t = threadIdx.x;
  const int v0 = blockIdx.x * 32;
  const int lane = t & 63, wv = t >> 6;

  { // stage: wave wv rows wv*8..+7; lanes 0-31 direct (cols 0-127),
    // lanes 32-63 flipped var half (cols 128-255); hi/lo split
    const int half = lane >> 5, f4 = (lane & 31) * 4;
    #pragma unroll
    for(int i=0;i<8;i++){
      int r = wv*8 + i;
      float4 a = *(const float4*)&Lh[(size_t)(v0 + r + (half ? HALFL : 0))*128 + f4];
      unsigned short hx=f2b(a.x), hy=f2b(a.y), hz=f2b(a.z), hw=f2b(a.w);
      unsigned short lx=f2b(a.x-b2f(hx)), ly=f2b(a.y-b2f(hy));
      unsigned short lz=f2b(a.z-b2f(hz)), lw=f2b(a.w-b2f(hw));
      int off = half*128 + f4;
      *(uint2*)&xs[0][r][off] = make_uint2(((unsigned int)hy<<16)|hx, ((unsigned int)hw<<16)|hz);
      *(uint2*)&xs[1][r][off] = make_uint2(((unsigned int)ly<<16)|lx, ((unsigned int)lw<<16)|lz);
    }
  }
  __syncthreads();

  const int rt  = wv & 1;
  const int ntb = (wv >> 1) * 8;          // 16 n-tiles split across wave pairs
  const int am  = rt*16 + (lane & 15);
  const int ak  = (lane >> 4) * 8;

  for(int hd=0; hd<2; hd++){
    const short8* Bh = (const short8*)(hd ? Wch : Wdh);
    const short8* Bl = (const short8*)(hd ? Wcl : Wdl);
    const float* b1 = hd ? b1c : b1d;
    const float* W2 = hd ? W2c : W2d;
    const float  bb = hd ? b2c[0] : b2d[0];

    f32x4 acc[8];
    #pragma unroll
    for(int ntl=0; ntl<8; ntl++){
      float bv = b1[(ntb+ntl)*16 + (lane & 15)];
      acc[ntl] = (f32x4){bv, bv, bv, bv};
    }
    #pragma unroll
    for(int kt=0; kt<8; kt++){
      short8 ah = *(const short8*)&xs[0][am][kt*32 + ak];
      short8 al = *(const short8*)&xs[1][am][kt*32 + ak];
      #pragma unroll
      for(int ntl=0; ntl<8; ntl++){
        int g = ntb + ntl;
        short8 bh = Bh[(g*8 + kt)*64 + lane];
        short8 bl = Bl[(g*8 + kt)*64 + lane];
        acc[ntl] = __builtin_amdgcn_mfma_f32_16x16x32_bf16(ah, bh, acc[ntl], 0, 0, 0);
        acc[ntl] = __builtin_amdgcn_mfma_f32_16x16x32_bf16(ah, bl, acc[ntl], 0, 0, 0);
        acc[ntl] = __builtin_amdgcn_mfma_f32_16x16x32_bf16(al, bh, acc[ntl], 0, 0, 0);
      }
    }
    // output layer: p[reg] = sum_cols relu(h)*w2; reduce 16 lanes per quad
    float w2v[8];
    #pragma unroll
    for(int ntl=0; ntl<8; ntl++) w2v[ntl] = W2[(ntb+ntl)*16 + (lane & 15)];
    float p[4];
    #pragma unroll
    for(int reg=0; reg<4; reg++){
      float s = 0.f;
      #pragma unroll
      for(int ntl=0; ntl<8; ntl++) s = fmaf(fmaxf(acc[ntl][reg], 0.f), w2v[ntl], s);
      #pragma unroll
      for(int m=1; m<16; m<<=1) s += __shfl_xor(s, m, 64);
      p[reg] = s;
    }
    if((lane & 15) == 0){
      int rowb = rt*16 + ((lane >> 4) << 2);
      #pragma unroll
      for(int reg=0; reg<4; reg++) hpart[rowb + reg][wv >> 1] = p[reg];
    }
    __syncthreads();
    if(t < 32) out[(size_t)hd*NVAR + v0 + t] = hpart[t][0] + hpart[t][1] + bb;
    __syncthreads();
  }
}

// 64 thr, 8 clauses/block; normalizes C on load.
__global__ __launch_bounds__(64) void k_head_c(const float* __restrict__ C,
    const float* __restrict__ st,
    const float* __restrict__ W1, const float* __restrict__ b1,
    const float* __restrict__ W2, const float* __restrict__ b2,
    float* __restrict__ out){
  __shared__ float xs[8][128];
  const int t = threadIdx.x;
  const size_t c0 = (size_t)blockIdx.x * 8;
  { float m0 = st[256+t], m1 = st[256+t+64];
    float i0 = st[384+t], i1 = st[384+t+64];
    #pragma unroll
    for(int r=0;r<8;r++){
      xs[r][t]    = (C[(c0+r)*128 + t]      - m0) * i0;
      xs[r][t+64] = (C[(c0+r)*128 + t + 64] - m1) * i1;
    }
  }
  __syncthreads();
  float a0[8], a1[8];
  float bv0 = b1[t], bv1 = b1[t+64];
  #pragma unroll
  for(int r=0;r<8;r++){ a0[r]=bv0; a1[r]=bv1; }
  for(int k=0;k<128;k+=4){
    float w0[4], w1[4];
    #pragma unroll
    for(int kk=0;kk<4;kk++){ w0[kk]=W1[(size_t)(k+kk)*128 + t]; w1[kk]=W1[(size_t)(k+kk)*128 + t + 64]; }
    #pragma unroll
    for(int r=0;r<8;r++){
      float4 tv = *(const float4*)&xs[r][k];
      a0[r] += tv.x*w0[0]+tv.y*w0[1]+tv.z*w0[2]+tv.w*w0[3];
      a1[r] += tv.x*w1[0]+tv.y*w1[1]+tv.z*w1[2]+tv.w*w1[3];
    }
  }
  float w2a = W2[t], w2b = W2[t+64];
  float bb = b2[0];
  #pragma unroll
  for(int r=0;r<8;r++){
    float o = fmaxf(a0[r],0.f)*w2a + fmaxf(a1[r],0.f)*w2b;
    #pragma unroll
    for(int m=1;m<64;m<<=1) o += __shfl_xor(o,m,64);
    if(t == 0) out[c0 + r] = o + bb;
  }
}

// ---------------------------------------------------------------- launch
extern "C" void kernel_launch(void* const* d_in, const int* in_sizes, int n_in,
                              void* d_out, int out_size, void* d_ws, size_t ws_size,
                              hipStream_t stream){
  const float* L0   = (const float*)d_in[0];
  const float* lng  = (const float*)d_in[1];
  const float* lnb  = (const float*)d_in[2];
  const float* CuW1 = (const float*)d_in[3];
  const float* Cub1 = (const float*)d_in[4];
  const float* CuW2 = (const float*)d_in[5];
  const float* Cub2 = (const float*)d_in[6];
  const float* LuW1 = (const float*)d_in[7];
  const float* Lub1 = (const float*)d_in[8];
  const float* LuW2 = (const float*)d_in[9];
  const float* Lub2 = (const float*)d_in[10];
  const float* VdW1 = (const float*)d_in[11];
  const float* Vdb1 = (const float*)d_in[12];
  const float* VdW2 = (const float*)d_in[13];
  const float* Vdb2 = (const float*)d_in[14];
  const float* VcW1 = (const float*)d_in[15];
  const float* Vcb1 = (const float*)d_in[16];
  const float* VcW2 = (const float*)d_in[17];
  const float* Vcb2 = (const float*)d_in[18];
  const float* CsW1 = (const float*)d_in[19];
  const float* Csb1 = (const float*)d_in[20];
  const float* CsW2 = (const float*)d_in[21];
  const float* Csb2 = (const float*)d_in[22];
  const int* cidx = (const int*)d_in[23];
  const int* lidx = (const int*)d_in[24];
  const int  ne   = in_sizes[23];

  float* ws   = (float*)d_ws;
  float* Lh   = ws;                        // 25,600,000 f32
  float* C    = ws + 25600000;             // 38,400,000 f32 -> end 64,000,000
  float* st   = ws + 64000000;             // 512
  short* CW1h = (short*)(ws + 64000512);   // 65,536 bf16 each plane
  short* CW1m = (short*)(ws + 64033280);
  short* CW1l = (short*)(ws + 64066048);
  short* CW2h = (short*)(ws + 64098816);   // 32,768 each
  short* CW2m = (short*)(ws + 64115200);
  short* CW2l = (short*)(ws + 64131584);
  short* LW1h = (short*)(ws + 64147968);   // 16,384 each
  short* LW1m = (short*)(ws + 64156160);
  short* LW1l = (short*)(ws + 64164352);
  short* LW2h = (short*)(ws + 64172544);
  short* LW2m = (short*)(ws + 64180736);
  short* LW2l = (short*)(ws + 64188928);
  short* VdWh = (short*)(ws + 64197120);   // 65,536 each (2 planes)
  short* VdWl = (short*)(ws + 64229888);
  short* VcWh = (short*)(ws + 64262656);
  short* VcWl = (short*)(ws + 64295424);
  int*   ib   = (int*)(ws + 64328192);     // int region
  int*   Pc   = ib;                        // PAD_C = 300,032
  int*   Pl   = ib + PAD_C;                // PAD_L = 200,704
  int*   clit = ib + PAD_C + PAD_L;        // 1,000,000
  int*   lcl  = clit + 1000000;            // 1,000,000
  int*   psum = lcl + 1000000;             // 512
  // total ws ~= 267.3 MB
  float* out = (float*)d_out;              // fp32: drat|core|c_core

  k_init_lh<<<100000, 256, 0, stream>>>(L0, Lh);
  k_pack_w3<<<256, 256, 0, stream>>>(CuW1, CW1h, CW1m, CW1l, 256, 256);
  k_pack_w3<<<128, 256, 0, stream>>>(CuW2, CW2h, CW2m, CW2l, 256, 128);
  k_pack_w3<<<64, 256, 0, stream>>>(LuW1, LW1h, LW1m, LW1l, 128, 128);
  k_pack_w3<<<64, 256, 0, stream>>>(LuW2, LW2h, LW2m, LW2l, 128, 128);
  k_pack_w<<<256, 256, 0, stream>>>(VdW1, VdWh, VdWl, 256, 256);
  k_pack_w<<<256, 256, 0, stream>>>(VcW1, VcWh, VcWl, 256, 256);

  // CSR build (counting sort both directions)
  k_zero4<<<489, 256, 0, stream>>>((float4*)Pc, (PAD_C + PAD_L)/4);
  k_hist<<<(ne+255)/256, 256, 0, stream>>>(cidx, lidx, Pc, Pl, ne);
  k_scan_pass1<<<NB_C, 256, 0, stream>>>(Pc, psum);
  k_scan_pass2<<<1, 512, 0, stream>>>(psum, NB_C);
  k_scan_pass3<<<NB_C, 256, 0, stream>>>(Pc, psum);
  k_scan_pass1<<<NB_L, 256, 0, stream>>>(Pl, psum);
  k_scan_pass2<<<1, 512, 0, stream>>>(psum, NB_L);
  k_scan_pass3<<<NB_L, 256, 0, stream>>>(Pl, psum);
  k_fill<<<(ne+255)/256, 256, 0, stream>>>(cidx, lidx, Pc, Pl, clit, lcl, ne);

  for(int hop=0; hop<4; hop++){
    k_zero4<<<1, 256, 0, stream>>>((float4*)st, 128);
    k_clause_fused<<<9375, 256, 0, stream>>>(Pc, clit, Lh,
        CW1h, CW1m, CW1l, Cub1, CW2h, CW2m, CW2l, Cub2, C);
    k_colstats<<<512, 256, 0, stream>>>(C, st);
    k_finstats<<<1, 128, 0, stream>>>(st);
    k_lit_fused<<<6250, 256, 0, stream>>>(Pl, lcl, C, st,
        LW1h, LW1m, LW1l, Lub1, LW2h, LW2m, LW2l, Lub2, lng, lnb, Lh);
  }
  k_head_v<<<3125, 256, 0, stream>>>(Lh, VdWh, VdWl, Vdb1, VdW2, Vdb2,
                                     VcWh, VcWl, Vcb1, VcW2, Vcb2, out);
  k_head_c<<<37500, 64, 0, stream>>>(C, st, CsW1, Csb1, CsW2, Csb2, out + 200000);
}